// Round 27
// baseline (20.560 us; speedup 1.0000x reference)
//
#include <hip/hip_runtime.h>
#include <hip/hip_bf16.h>

#define N_X    65536
#define N_IND  1024
#define N_DESC 64
#define TILES  (N_IND / 16)       // 64 MFMA row-tiles (full z-panel)
#define L2E    1.4426950408889634f
#define L2E2   2.8853900817779268f
#define SKIP_THR (-60.0f)         // 2^-60 * 1024 * |alpha| ~ 4e-15 << tol

typedef __attribute__((ext_vector_type(8))) short  short8;
typedef __attribute__((ext_vector_type(4))) float  f32x4;
typedef __attribute__((ext_vector_type(2))) float  f32x2;

static __device__ __forceinline__ ushort f2bf(float f) {
    union { float f; unsigned u; } a; a.f = f;
    unsigned r = a.u + 0x7FFF + ((a.u >> 16) & 1);   // RNE to bf16
    return (ushort)(r >> 16);
}
static __device__ __forceinline__ float bf2f(ushort h) {
    union { unsigned u; float f; } a; a.u = (unsigned)h << 16;
    return a.f;
}

// ---------------------------------------------------------------------------
// Round 27 = R22 champion + K-HALF SKIP (purely-subtractive common path).
// Skip needs d > 41.6; the k-in-[0,32) partial distance is ~20*chi2_32
// (mean ~640; P(<41.6) ~ 5e-14) and d_full >= d_half, so ONE MFMA over the
// first K-half proves the skip:
//   arg_full <= L2E2*dot_half - xs2h - z2h <= L2E2*dot_half - xs2h - zminh
//   skip iff all lanes: fmaf(maxdot_h, L2E2, -xs2h) < SKIP_THR + zminh
// Common path/tile: 1 swizzled ds_read_b128 + 1 MFMA + max tree + fma + cmp
// (halves loop LDS reads 1024->512 b128/CU and MFMA issue). Fallback
// (~never: P~5e-14/pair) reads a1, completes the dot, runs the exact R12
// epilogue. New: z2h[] (cols 0-31 row-norms, emitted from the granule-0..3
// partial in the staging shfl tree) + xs2h (h=0 partial of x norm).
// Everything else identical to R22 (reproduced 4x at 20.17-20.25 us):
// early x loads, 2-deep pipelined staging, XOR-swizzled panel (byte colb ^=
// (row&7)<<4 both sides, rule #21), 16 waves x 16 cols (coverage audited),
// exact kept-path math. C/D: col = lane&15, row = 4*(lane>>4)+reg.
// ---------------------------------------------------------------------------
__global__ __launch_bounds__(1024) void igpr_fused(
        const float* __restrict__ x, const float* __restrict__ z,
        const float* __restrict__ alpha, const float* __restrict__ ls,
        float* __restrict__ out) {
    struct SM {
        uint4 zt[N_IND * 8];   // 1024 rows * 128 B = 128 KB (swizzled)
        float z2[N_IND];       // log2e * ||zw_i||^2        (full)
        float z2h[N_IND];      // log2e * ||zw_i[0:32]||^2  (K-half)
        float al[N_IND];       // alpha
    };
    __shared__ SM sm;          // 140.25 KB of the CU's 160 KB

    const int tid  = threadIdx.x;
    const int lane = tid & 63;
    const int wave = tid >> 6;
    const int p = lane & 15;          // x-col within strip / D col
    const int g = lane >> 4;          // k-group; D rows 4g..4g+3 (z-rows)
    const int j = blockIdx.x * 256 + wave * 16 + p;   // this lane's x column

    // ---- issue x loads immediately; consumed after z staging ----
    const float* xr = x + (size_t)j * N_DESC;
    float4 xv0 = *reinterpret_cast<const float4*>(xr + g * 8);
    float4 xv1 = *reinterpret_cast<const float4*>(xr + g * 8 + 4);
    float4 xv2 = *reinterpret_cast<const float4*>(xr + 32 + g * 8);
    float4 xv3 = *reinterpret_cast<const float4*>(xr + 32 + g * 8 + 4);
    float  alv = alpha[tid];          // N_IND == blockDim.x

    // ---- per-thread staging weights: cols gr*8 .. gr*8+7 ----
    const int gr = tid & 7;           // granule column-group (fixed per thread)
    const int row_base = tid >> 3;    // row = rb*128 + row_base
    float wz[8];
#pragma unroll
    for (int e = 0; e < 8; ++e) wz[e] = __expf(-0.5f * ls[gr * 8 + e]);

    // ---- z staging: 8 granules, 2-deep pipelined, swizzled dest ----
    char* zbw = reinterpret_cast<char*>(sm.zt);

#define ZLD(rb, A, B)                                                          \
    {                                                                          \
        const float* zp_ = z + (size_t)((rb) * 128 + row_base) * 64 + gr * 8;  \
        A = *reinterpret_cast<const float4*>(zp_);                             \
        B = *reinterpret_cast<const float4*>(zp_ + 4);                         \
    }
#define ZCVT(rb, A, B)                                                         \
    {                                                                          \
        float vv_[8] = {A.x, A.y, A.z, A.w, B.x, B.y, B.z, B.w};               \
        ushort hb_[8]; float sq_ = 0.f;                                        \
        _Pragma("unroll")                                                      \
        for (int e = 0; e < 8; ++e) {                                          \
            ushort h_ = f2bf(vv_[e] * wz[e]);                                  \
            hb_[e] = h_;                                                       \
            float vr_ = bf2f(h_);                                              \
            sq_ = fmaf(vr_, vr_, sq_);                                         \
        }                                                                      \
        uint4 u_ = make_uint4(                                                 \
            (unsigned)hb_[0] | ((unsigned)hb_[1] << 16),                       \
            (unsigned)hb_[2] | ((unsigned)hb_[3] << 16),                       \
            (unsigned)hb_[4] | ((unsigned)hb_[5] << 16),                       \
            (unsigned)hb_[6] | ((unsigned)hb_[7] << 16));                      \
        int row_ = (rb) * 128 + row_base;                                      \
        int sw_  = row_ * 128 + ((gr * 16) ^ ((row_ & 7) << 4));               \
        *reinterpret_cast<uint4*>(zbw + sw_) = u_;                             \
        sq_ += __shfl_xor(sq_, 1);                                             \
        sq_ += __shfl_xor(sq_, 2);                                             \
        if (gr == 0) sm.z2h[row_] = sq_ * L2E;   /* cols 0-31 partial */       \
        sq_ += __shfl_xor(sq_, 4);                                             \
        if (gr == 0) sm.z2[row_] = sq_ * L2E;                                  \
    }

    float4 cA, cB, nA, nB;
    ZLD(0, cA, cB)
    ZLD(1, nA, nB)
    ZCVT(0, cA, cB)  ZLD(2, cA, cB)
    ZCVT(1, nA, nB)  ZLD(3, nA, nB)
    ZCVT(2, cA, cB)  ZLD(4, cA, cB)
    ZCVT(3, nA, nB)  ZLD(5, nA, nB)
    ZCVT(4, cA, cB)  ZLD(6, cA, cB)
    ZCVT(5, nA, nB)  ZLD(7, nA, nB)
    ZCVT(6, cA, cB)
    ZCVT(7, nA, nB)
#undef ZLD
#undef ZCVT

    sm.al[tid] = alv;

    // ---- convert x (loads long in flight) + xs2 / xs2h ----
    short8 b0, b1;
    float xs2, xs2h;
    {
        float wx[16];
#pragma unroll
        for (int h = 0; h < 2; ++h)
#pragma unroll
            for (int e = 0; e < 8; ++e)
                wx[h * 8 + e] = __expf(-0.5f * ls[h * 32 + g * 8 + e]);
        float vv[16] = {xv0.x, xv0.y, xv0.z, xv0.w, xv1.x, xv1.y, xv1.z, xv1.w,
                        xv2.x, xv2.y, xv2.z, xv2.w, xv3.x, xv3.y, xv3.z, xv3.w};
        float sq0 = 0.f, sq1 = 0.f;
        short8 bb[2];
#pragma unroll
        for (int h = 0; h < 2; ++h)
#pragma unroll
            for (int e = 0; e < 8; ++e) {
                ushort hh = f2bf(vv[h * 8 + e] * wx[h * 8 + e]);
                bb[h][e] = (short)hh;
                float xv = bf2f(hh);
                if (h == 0) sq0 = fmaf(xv, xv, sq0);
                else        sq1 = fmaf(xv, xv, sq1);
            }
        b0 = bb[0]; b1 = bb[1];
        sq0 += __shfl_xor(sq0, 16);
        sq0 += __shfl_xor(sq0, 32);
        sq1 += __shfl_xor(sq1, 16);
        sq1 += __shfl_xor(sq1, 32);
        xs2h = sq0 * L2E;                // k in [0,32)
        xs2  = (sq0 + sq1) * L2E;        // full
    }

    __syncthreads();   // z-panel + z2 + z2h + al ready (read-only from here)

    // ---- wave-scalar half-norm bound: zminh = min z2h over all rows ----
    float zminh;
    {
        float mn = sm.z2h[lane];
#pragma unroll
        for (int i = 1; i < 16; ++i) mn = fminf(mn, sm.z2h[lane + 64 * i]);
        mn = fminf(mn, __shfl_xor(mn, 1));
        mn = fminf(mn, __shfl_xor(mn, 2));
        mn = fminf(mn, __shfl_xor(mn, 4));
        mn = fminf(mn, __shfl_xor(mn, 8));
        mn = fminf(mn, __shfl_xor(mn, 16));
        mn = fminf(mn, __shfl_xor(mn, 32));
        zminh = mn;
    }
    const float thr = SKIP_THR + zminh;  // per-lane test subtracts xs2h

    const char* zb = reinterpret_cast<const char*>(sm.zt);
    const int rb0 = p * 128 + ((16 * g)      ^ ((p & 7) << 4));
    const int rb1 = p * 128 + ((64 + 16 * g) ^ ((p & 7) << 4));

    f32x2 accJ = {0.f, 0.f};
    const f32x2 xs2p = {xs2, xs2};

#pragma unroll 4
    for (int it = 0; it < TILES; ++it) {
        short8 a0 = *reinterpret_cast<const short8*>(zb + it * 2048 + rb0);

        f32x4 th = {0.f, 0.f, 0.f, 0.f};
        th = __builtin_amdgcn_mfma_f32_16x16x32_bf16(a0, b0, th, 0, 0, 0);

        float maxdot = fmaxf(fmaxf(th[0], th[1]), fmaxf(th[2], th[3]));

        // skip iff every pair's K-half arg bound is below threshold:
        //   arg_full <= L2E2*dot_h - xs2h - z2h <= L2E2*maxdot - xs2h - zminh
        if (!__all(fmaf(maxdot, L2E2, -xs2h) < thr)) {
            // rare path (~P 5e-14/pair): finish the dot, exact R12 epilogue
            short8 a1 = *reinterpret_cast<const short8*>(zb + it * 2048 + rb1);
            f32x4 t = __builtin_amdgcn_mfma_f32_16x16x32_bf16(a1, b1, th, 0, 0, 0);

            float4 z2 = *reinterpret_cast<const float4*>(&sm.z2[it * 16 + g * 4]);
            float4 a4 = *reinterpret_cast<const float4*>(&sm.al[it * 16 + g * 4]);
            f32x2 z2p0 = {z2.x, z2.y}, z2p1 = {z2.z, z2.w};
            f32x2 d0 = {t[0], t[1]}, d1 = {t[2], t[3]};
            f32x2 arg0 = d0 * L2E2 - (z2p0 + xs2p);
            f32x2 arg1 = d1 * L2E2 - (z2p1 + xs2p);
            f32x2 pv0 = {__builtin_amdgcn_exp2f(arg0.x),
                         __builtin_amdgcn_exp2f(arg0.y)};
            f32x2 pv1 = {__builtin_amdgcn_exp2f(arg1.x),
                         __builtin_amdgcn_exp2f(arg1.y)};
            f32x2 a4p0 = {a4.x, a4.y}, a4p1 = {a4.z, a4.w};
            accJ = accJ + a4p0 * pv0;              // pk_fma
            accJ = accJ + a4p1 * pv1;              // pk_fma
        }
    }

    float r = accJ.x + accJ.y;
    r += __shfl_xor(r, 16);
    r += __shfl_xor(r, 32);
    if (g == 0) out[j] = r;
}

extern "C" void kernel_launch(void* const* d_in, const int* in_sizes, int n_in,
                              void* d_out, int out_size, void* d_ws, size_t ws_size,
                              hipStream_t stream) {
    const float* x     = (const float*)d_in[0];   // (65536, 64)
    const float* z     = (const float*)d_in[1];   // (1024, 64)
    const float* alpha = (const float*)d_in[2];   // (1024,)
    const float* ls    = (const float*)d_in[3];   // (64,)
    float* out = (float*)d_out;                   // (65536, 1)

    igpr_fused<<<dim3(N_X / 256), dim3(1024), 0, stream>>>(x, z, alpha, ls, out);
}

// Round 28
// 20.143 us; speedup vs baseline: 1.0207x; 1.0207x over previous
//
#include <hip/hip_runtime.h>
#include <hip/hip_bf16.h>

#define N_X    65536
#define N_IND  1024
#define N_DESC 64
#define TILES  (N_IND / 16)       // 64 MFMA row-tiles (full z-panel)
#define L2E    1.4426950408889634f
#define L2E2   2.8853900817779268f
#define SKIP_THR (-60.0f)         // 2^-60 * 1024 * |alpha| ~ 4e-15 << tol

typedef __attribute__((ext_vector_type(8))) short  short8;
typedef __attribute__((ext_vector_type(4))) float  f32x4;
typedef __attribute__((ext_vector_type(2))) float  f32x2;

static __device__ __forceinline__ ushort f2bf(float f) {
    union { float f; unsigned u; } a; a.f = f;
    unsigned r = a.u + 0x7FFF + ((a.u >> 16) & 1);   // RNE to bf16
    return (ushort)(r >> 16);
}
static __device__ __forceinline__ float bf2f(ushort h) {
    union { unsigned u; float f; } a; a.u = (unsigned)h << 16;
    return a.f;
}

// ---------------------------------------------------------------------------
// FINAL (= Round 22 champion; reproduced 4x at 20.17-20.25 us, absmax 0.0,
// full output coverage audited: 16 waves x 16 cols x 256 blocks = 65536).
// Structure: single fused dispatch, 1024-thr blocks (16 waves, 1 block/CU),
// grid 256. Per block: full weighted z-panel f32->bf16 converted in-register
// and staged once into 128 KB XOR-swizzled LDS (2-deep pipelined granule
// loads; x loads issued first, in flight under staging). Each wave owns 16
// x-columns; loop over 64 tiles: 2 swizzled conflict-free ds_read_b128 +
// 2 chained mfma_16x16x32_bf16 + 4-op skip test vs wave-scalar bound
//   skip iff L2E2*maxdot < SKIP_THR + xs2 + zmin   (zmin = min z2, sound)
// (each skipped term < 2^-60, total < 4e-15 — below f32 accumulation
// granularity; exact epilogue on the kept path if it ever fires).
// Swizzle: byte colb ^= (row&7)<<4 on BOTH write and read (rule #21).
// C/D: col = lane&15 (x-col), row = 4*(lane>>4)+reg (z-row).
// Plateau evidence: R13 rep-profile (loop LDS-issue-bound, staging
// latency-bound); R15/R19/R20 proportional LDS-delta responses; R27 K-half
// null (loop no longer binding); R16/R17/R18/R21/R23/R24/R25/R27
// restructurings all regressed or null — VALU/launch/register/ws-dirty-read
// taxes exceed their LDS/latency savings at this problem shape.
// ---------------------------------------------------------------------------
__global__ __launch_bounds__(1024) void igpr_fused(
        const float* __restrict__ x, const float* __restrict__ z,
        const float* __restrict__ alpha, const float* __restrict__ ls,
        float* __restrict__ out) {
    struct SM {
        uint4 zt[N_IND * 8];   // 1024 rows * 128 B = 128 KB (swizzled)
        float z2[N_IND];       // log2e * ||zw_i||^2
        float al[N_IND];       // alpha
    };
    __shared__ SM sm;          // 136 KB of the CU's 160 KB

    const int tid  = threadIdx.x;
    const int lane = tid & 63;
    const int wave = tid >> 6;
    const int p = lane & 15;          // x-col within strip / D col
    const int g = lane >> 4;          // k-group; D rows 4g..4g+3 (z-rows)
    const int j = blockIdx.x * 256 + wave * 16 + p;   // this lane's x column

    // ---- issue x loads immediately; consumed after z staging ----
    const float* xr = x + (size_t)j * N_DESC;
    float4 xv0 = *reinterpret_cast<const float4*>(xr + g * 8);
    float4 xv1 = *reinterpret_cast<const float4*>(xr + g * 8 + 4);
    float4 xv2 = *reinterpret_cast<const float4*>(xr + 32 + g * 8);
    float4 xv3 = *reinterpret_cast<const float4*>(xr + 32 + g * 8 + 4);
    float  alv = alpha[tid];          // N_IND == blockDim.x

    // ---- per-thread staging weights: cols gr*8 .. gr*8+7 ----
    const int gr = tid & 7;           // granule column-group (fixed per thread)
    const int row_base = tid >> 3;    // row = rb*128 + row_base
    float wz[8];
#pragma unroll
    for (int e = 0; e < 8; ++e) wz[e] = __expf(-0.5f * ls[gr * 8 + e]);

    // ---- z staging: 8 granules, 2-deep pipelined, swizzled dest ----
    char* zbw = reinterpret_cast<char*>(sm.zt);

#define ZLD(rb, A, B)                                                          \
    {                                                                          \
        const float* zp_ = z + (size_t)((rb) * 128 + row_base) * 64 + gr * 8;  \
        A = *reinterpret_cast<const float4*>(zp_);                             \
        B = *reinterpret_cast<const float4*>(zp_ + 4);                         \
    }
#define ZCVT(rb, A, B)                                                         \
    {                                                                          \
        float vv_[8] = {A.x, A.y, A.z, A.w, B.x, B.y, B.z, B.w};               \
        ushort hb_[8]; float sq_ = 0.f;                                        \
        _Pragma("unroll")                                                      \
        for (int e = 0; e < 8; ++e) {                                          \
            ushort h_ = f2bf(vv_[e] * wz[e]);                                  \
            hb_[e] = h_;                                                       \
            float vr_ = bf2f(h_);                                              \
            sq_ = fmaf(vr_, vr_, sq_);                                         \
        }                                                                      \
        uint4 u_ = make_uint4(                                                 \
            (unsigned)hb_[0] | ((unsigned)hb_[1] << 16),                       \
            (unsigned)hb_[2] | ((unsigned)hb_[3] << 16),                       \
            (unsigned)hb_[4] | ((unsigned)hb_[5] << 16),                       \
            (unsigned)hb_[6] | ((unsigned)hb_[7] << 16));                      \
        int row_ = (rb) * 128 + row_base;                                      \
        int sw_  = row_ * 128 + ((gr * 16) ^ ((row_ & 7) << 4));               \
        *reinterpret_cast<uint4*>(zbw + sw_) = u_;                             \
        sq_ += __shfl_xor(sq_, 1);                                             \
        sq_ += __shfl_xor(sq_, 2);                                             \
        sq_ += __shfl_xor(sq_, 4);                                             \
        if (gr == 0) sm.z2[row_] = sq_ * L2E;                                  \
    }

    float4 cA, cB, nA, nB;
    ZLD(0, cA, cB)
    ZLD(1, nA, nB)
    ZCVT(0, cA, cB)  ZLD(2, cA, cB)
    ZCVT(1, nA, nB)  ZLD(3, nA, nB)
    ZCVT(2, cA, cB)  ZLD(4, cA, cB)
    ZCVT(3, nA, nB)  ZLD(5, nA, nB)
    ZCVT(4, cA, cB)  ZLD(6, cA, cB)
    ZCVT(5, nA, nB)  ZLD(7, nA, nB)
    ZCVT(6, cA, cB)
    ZCVT(7, nA, nB)
#undef ZLD
#undef ZCVT

    sm.al[tid] = alv;

    // ---- convert x (loads long in flight) + xs2 ----
    short8 b0, b1;
    float xs2;
    {
        float wx[16];
#pragma unroll
        for (int h = 0; h < 2; ++h)
#pragma unroll
            for (int e = 0; e < 8; ++e)
                wx[h * 8 + e] = __expf(-0.5f * ls[h * 32 + g * 8 + e]);
        float vv[16] = {xv0.x, xv0.y, xv0.z, xv0.w, xv1.x, xv1.y, xv1.z, xv1.w,
                        xv2.x, xv2.y, xv2.z, xv2.w, xv3.x, xv3.y, xv3.z, xv3.w};
        float sq = 0.f;
        short8 bb[2];
#pragma unroll
        for (int h = 0; h < 2; ++h)
#pragma unroll
            for (int e = 0; e < 8; ++e) {
                ushort hh = f2bf(vv[h * 8 + e] * wx[h * 8 + e]);
                bb[h][e] = (short)hh;
                float xv = bf2f(hh);
                sq = fmaf(xv, xv, sq);
            }
        b0 = bb[0]; b1 = bb[1];
        sq += __shfl_xor(sq, 16);
        sq += __shfl_xor(sq, 32);
        xs2 = sq * L2E;
    }

    __syncthreads();   // z-panel + z2 + al ready (LDS read-only from here)

    // ---- wave-scalar skip bound: zmin = min z2 over all rows ----
    float zmin;
    {
        float mn = sm.z2[lane];
#pragma unroll
        for (int i = 1; i < 16; ++i) mn = fminf(mn, sm.z2[lane + 64 * i]);
        mn = fminf(mn, __shfl_xor(mn, 1));
        mn = fminf(mn, __shfl_xor(mn, 2));
        mn = fminf(mn, __shfl_xor(mn, 4));
        mn = fminf(mn, __shfl_xor(mn, 8));
        mn = fminf(mn, __shfl_xor(mn, 16));
        mn = fminf(mn, __shfl_xor(mn, 32));
        zmin = mn;
    }
    const float thr = SKIP_THR + xs2 + zmin;   // skip iff L2E2*maxdot < thr

    const char* zb = reinterpret_cast<const char*>(sm.zt);
    const int rb0 = p * 128 + ((16 * g)      ^ ((p & 7) << 4));
    const int rb1 = p * 128 + ((64 + 16 * g) ^ ((p & 7) << 4));

    f32x2 accJ = {0.f, 0.f};
    const f32x2 xs2p = {xs2, xs2};

#pragma unroll 4
    for (int it = 0; it < TILES; ++it) {
        short8 a0 = *reinterpret_cast<const short8*>(zb + it * 2048 + rb0);
        short8 a1 = *reinterpret_cast<const short8*>(zb + it * 2048 + rb1);

        f32x4 t = {0.f, 0.f, 0.f, 0.f};
        t = __builtin_amdgcn_mfma_f32_16x16x32_bf16(a0, b0, t, 0, 0, 0);
        t = __builtin_amdgcn_mfma_f32_16x16x32_bf16(a1, b1, t, 0, 0, 0);

        float maxdot = fmaxf(fmaxf(t[0], t[1]), fmaxf(t[2], t[3]));

        if (!__all(maxdot * L2E2 < thr)) {
            // rare path: a real contribution may exist in this tile
            float4 z2 = *reinterpret_cast<const float4*>(&sm.z2[it * 16 + g * 4]);
            float4 a4 = *reinterpret_cast<const float4*>(&sm.al[it * 16 + g * 4]);
            f32x2 z2p0 = {z2.x, z2.y}, z2p1 = {z2.z, z2.w};
            f32x2 d0 = {t[0], t[1]}, d1 = {t[2], t[3]};
            f32x2 arg0 = d0 * L2E2 - (z2p0 + xs2p);
            f32x2 arg1 = d1 * L2E2 - (z2p1 + xs2p);
            f32x2 pv0 = {__builtin_amdgcn_exp2f(arg0.x),
                         __builtin_amdgcn_exp2f(arg0.y)};
            f32x2 pv1 = {__builtin_amdgcn_exp2f(arg1.x),
                         __builtin_amdgcn_exp2f(arg1.y)};
            f32x2 a4p0 = {a4.x, a4.y}, a4p1 = {a4.z, a4.w};
            accJ = accJ + a4p0 * pv0;              // pk_fma
            accJ = accJ + a4p1 * pv1;              // pk_fma
        }
    }

    float r = accJ.x + accJ.y;
    r += __shfl_xor(r, 16);
    r += __shfl_xor(r, 32);
    if (g == 0) out[j] = r;
}

extern "C" void kernel_launch(void* const* d_in, const int* in_sizes, int n_in,
                              void* d_out, int out_size, void* d_ws, size_t ws_size,
                              hipStream_t stream) {
    const float* x     = (const float*)d_in[0];   // (65536, 64)
    const float* z     = (const float*)d_in[1];   // (1024, 64)
    const float* alpha = (const float*)d_in[2];   // (1024,)
    const float* ls    = (const float*)d_in[3];   // (64,)
    float* out = (float*)d_out;                   // (65536, 1)

    igpr_fused<<<dim3(N_X / 256), dim3(1024), 0, stream>>>(x, z, alpha, ls, out);
}